// Round 6
// baseline (751.130 us; speedup 1.0000x reference)
//
#include <hip/hip_runtime.h>
#include <hip/hip_cooperative_groups.h>

// MessagePassingNet on MI355X — Round 6:
//   * edge kernel: wave-autonomous (16 edges/wave), ZERO barriers — TLP hides
//     the random gather latency (R5 lesson: barrier-coupled pipelining spills)
//   * all preprocessing (init, weight pack, counting sort, atom_pre) fused
//     into ONE cooperative kernel -> 3 launches total
//   * split-bf16 (hi/lo, 3-MFMA) everywhere; layer-0 hoisted per-atom

namespace cg = cooperative_groups;

constexpr int N_ATOMS = 131072;
constexpr int N_EDGES = 1048576;
constexpr int DD      = 64;
constexpr int OUTD    = 16;
constexpr int SH      = 72;   // halfword row stride for 64-wide hi/lo tiles
constexpr int CBLK    = 512;  // cooperative grid size (2 blocks/CU — safe co-residency)

typedef __bf16 bf16x8 __attribute__((ext_vector_type(8)));
typedef float  f32x4  __attribute__((ext_vector_type(4)));

#define DEV_INLINE __device__ __forceinline__

DEV_INLINE float relu(float x) { return x > 0.f ? x : 0.f; }

DEV_INLINE unsigned short bfbits(float x) {
  __bf16 h = (__bf16)x;
  return __builtin_bit_cast(unsigned short, h);
}
DEV_INLINE float bfval(unsigned short u) {
  unsigned int v = ((unsigned int)u) << 16;
  return __builtin_bit_cast(float, v);
}
DEV_INLINE f32x4 mfma16(bf16x8 a, bf16x8 b, f32x4 c) {
  return __builtin_amdgcn_mfma_f32_16x16x32_bf16(a, b, c, 0, 0, 0);
}
DEV_INLINE bf16x8 ldfrag(const unsigned short* p) { return *(const bf16x8*)p; }

// ===========================================================================
// coop_prep: one cooperative kernel doing
//   p0: zero new_states + counters; pack weights (hi/lo, B-fragment order)
//   p1: histogram of edge_dst
//   p2: per-block chunk totals (256 counters/block)
//   p3: block 0 exclusive-scans 512 partials
//   p4: cursor = global exclusive prefix per atom
//   p5: scatter edge ids into dst-sorted order
//   p6: atom_pre — Yd = X·W0d + b0, Ys = X·W0s  (grid-stride, MFMA)
// Weight sections (4096 elems each): 0=W0 dst half, 1=W0 src half, 2=W1,
// 3=W2, 4=FC1, 5=FC2.  fo(sec,j,s,l) = sec*4096 + ((j*2+s)*64 + l)*8.
// ===========================================================================
__global__ __launch_bounds__(256, 4)
void coop_prep(const float* __restrict__ atom_states,
               const int* __restrict__ edge_dst,
               const float* __restrict__ w0, const float* __restrict__ w1,
               const float* __restrict__ w2, const float* __restrict__ f1,
               const float* __restrict__ f2, const float* __restrict__ b0,
               unsigned short* __restrict__ whi, unsigned short* __restrict__ wlo,
               int* __restrict__ counters, int* __restrict__ cursor,
               int* __restrict__ partial, int* __restrict__ eids,
               float* __restrict__ new_states,
               float* __restrict__ Yd, float* __restrict__ Ys)
{
  cg::grid_group grid = cg::this_grid();
  const int t   = threadIdx.x;
  const int b   = blockIdx.x;
  const int tid = b * 256 + t;          // 0 .. 131071
  const int NT  = CBLK * 256;

  __shared__ int sS[256];
  __shared__ __align__(16) unsigned short Xh[64 * SH];
  __shared__ __align__(16) unsigned short Xl[64 * SH];

  // ---------------- phase 0: init + weight pack ----------------
  {
    float4* ns4 = (float4*)new_states;
    const int n4 = N_ATOMS * DD / 4;
    for (int i = tid; i < n4; i += NT) ns4[i] = make_float4(0.f, 0.f, 0.f, 0.f);
    if (tid < N_ATOMS / 4) ((int4*)counters)[tid] = make_int4(0, 0, 0, 0);
    if (tid < 3072) {
      int sec = tid >> 9, rel = tid & 511;
      const float* w; int rowoff = 0;
      switch (sec) {
        case 0: w = w0; rowoff = 0;  break;
        case 1: w = w0; rowoff = 64; break;
        case 2: w = w1; break;
        case 3: w = w2; break;
        case 4: w = f1; break;
        default: w = f2; break;
      }
      const int tile = rel >> 6, lane = rel & 63;
      const int j = tile >> 1, s = tile & 1;
      const int n  = j * 16 + (lane & 15);
      const int kb = s * 32 + (lane >> 4) * 8;
      const int out = sec * 4096 + (tile * 64 + lane) * 8;
#pragma unroll
      for (int i = 0; i < 8; ++i) {
        float v = w[(rowoff + kb + i) * 64 + n];
        unsigned short h = bfbits(v);
        whi[out + i] = h;
        wlo[out + i] = bfbits(v - bfval(h));
      }
    }
  }
  grid.sync();

  // ---------------- phase 1: histogram ----------------
  for (int i = tid; i < N_EDGES; i += NT) atomicAdd(&counters[edge_dst[i]], 1);
  grid.sync();

  // ---------------- phase 2: per-block chunk totals ----------------
  {
    int v = counters[b * 256 + t];
    sS[t] = v; __syncthreads();
    for (int off = 128; off > 0; off >>= 1) {
      if (t < off) sS[t] += sS[t + off];
      __syncthreads();
    }
    if (t == 0) partial[b] = sS[0];
  }
  grid.sync();

  // ---------------- phase 3: block 0 exclusive-scans 512 partials ----------
  if (b == 0) {
    int a0v = partial[2 * t], a1v = partial[2 * t + 1];
    int s = a0v + a1v;
    sS[t] = s; __syncthreads();
    for (int off = 1; off < 256; off <<= 1) {
      int x = (t >= off) ? sS[t - off] : 0;
      __syncthreads();
      sS[t] += x;
      __syncthreads();
    }
    int base = sS[t] - s;
    partial[2 * t]     = base;
    partial[2 * t + 1] = base + a0v;
  }
  grid.sync();

  // ---------------- phase 4: cursor = exclusive prefix ----------------
  {
    int v = counters[b * 256 + t];
    sS[t] = v; __syncthreads();
    for (int off = 1; off < 256; off <<= 1) {
      int x = (t >= off) ? sS[t - off] : 0;
      __syncthreads();
      sS[t] += x;
      __syncthreads();
    }
    cursor[b * 256 + t] = partial[b] + sS[t] - v;
  }
  grid.sync();

  // ---------------- phase 5: scatter ----------------
  for (int i = tid; i < N_EDGES; i += NT) {
    int pos = atomicAdd(&cursor[edge_dst[i]], 1);
    eids[pos] = i;
  }
  // (no sync: phase 6 does not read sort outputs)

  // ---------------- phase 6: atom_pre (grid-stride) ----------------
  {
    const int l    = t & 63;
    const int w    = t >> 6;
    const int mrow = w * 16 + (l & 15);
    const int kq   = (l >> 4) * 8;
    const int cc   = l & 15;
    const int sr   = t >> 2;          // stage row (in-band: wave w owns rows w*16..+15)
    const int sk0  = (t & 3) * 16;

    for (int tile = b; tile < N_ATOMS / 64; tile += CBLK) {
      const int a0 = tile * 64;
      // stage + hi/lo split (band-local -> no barrier; same-wave in-order LDS)
      {
        const float4* s4 = (const float4*)(atom_states + (size_t)(a0 + sr) * DD + sk0);
#pragma unroll
        for (int f = 0; f < 4; ++f) {
          float4 v = s4[f];
          ushort4 h, lo;
          h.x = bfbits(v.x); lo.x = bfbits(v.x - bfval(h.x));
          h.y = bfbits(v.y); lo.y = bfbits(v.y - bfval(h.y));
          h.z = bfbits(v.z); lo.z = bfbits(v.z - bfval(h.z));
          h.w = bfbits(v.w); lo.w = bfbits(v.w - bfval(h.w));
          *(ushort4*)&Xh[sr * SH + sk0 + f * 4] = h;
          *(ushort4*)&Xl[sr * SH + sk0 + f * 4] = lo;
        }
      }
#pragma unroll
      for (int side = 0; side < 2; ++side) {
        f32x4 acc[4];
#pragma unroll
        for (int j = 0; j < 4; ++j) acc[j] = (f32x4){0.f, 0.f, 0.f, 0.f};
#pragma unroll
        for (int s = 0; s < 2; ++s) {
          bf16x8 ah = ldfrag(&Xh[mrow * SH + s * 32 + kq]);
          bf16x8 al = ldfrag(&Xl[mrow * SH + s * 32 + kq]);
#pragma unroll
          for (int j = 0; j < 4; ++j) {
            const int fo = side * 4096 + ((j * 2 + s) * 64 + l) * 8;
            bf16x8 bh = ldfrag(whi + fo);
            bf16x8 bl = ldfrag(wlo + fo);
            acc[j] = mfma16(al, bh, acc[j]);
            acc[j] = mfma16(ah, bl, acc[j]);
            acc[j] = mfma16(ah, bh, acc[j]);
          }
        }
        float* Y = side ? Ys : Yd;
#pragma unroll
        for (int j = 0; j < 4; ++j) {
          const int   c  = j * 16 + cc;
          const float bb = side ? 0.f : b0[c];
#pragma unroll
          for (int i = 0; i < 4; ++i) {
            const int r = w * 16 + (l >> 4) * 4 + i;
            Y[(size_t)(a0 + r) * DD + c] = acc[j][i] + bb;
          }
        }
      }
    }
  }
}

// ===========================================================================
// edge_kernel_v4: wave-autonomous, barrier-free. Each wave owns 16 dst-sorted
// edges: indices via __shfl, own LDS slice (h1/h2 hi|lo, msg aliases h1),
// 16x64 GEMMs via 16x16x32 split-bf16 MFMA, per-wave segmented reduction.
// NO s_barrier anywhere -> waves slip freely, TLP hides gather latency.
// ===========================================================================
__global__ __launch_bounds__(256, 4)
void edge_kernel_v4(const float* __restrict__ Yd,
                    const float* __restrict__ Ys,
                    const int* __restrict__ edge_src,
                    const int* __restrict__ edge_dst,
                    const int* __restrict__ eids,
                    const unsigned short* __restrict__ whi,
                    const unsigned short* __restrict__ wlo,
                    const float* __restrict__ b1,
                    const float* __restrict__ b2,
                    float* __restrict__ new_states)
{
  // per-wave slices: [hi 16*SH | lo 16*SH] halfwords; msg fp32 aliases slice
  __shared__ __align__(16) unsigned short H1[4][2 * 16 * SH];
  __shared__ __align__(16) unsigned short H2[4][2 * 16 * SH];

  const int t = threadIdx.x;
  const int w = t >> 6;
  const int l = t & 63;
  const int e0 = blockIdx.x * 64 + w * 16;

  unsigned short* h1 = H1[w];            // hi at [0), lo at [16*SH)
  unsigned short* h2 = H2[w];
  float* msg = (float*)H1[w];            // 16 rows x SH floats (1152 floats = slice)

  // ---- per-lane index load (lanes 0..15 hold this wave's 16 edges)
  int d = 0, s = 0;
  if (l < 16) {
    int eid = eids[e0 + l];
    d = edge_dst[eid];
    s = edge_src[eid];
  }

  // ---- gather h1 = relu(Yd[dst] + Ys[src]), hi/lo split (lane -> edge l>>2)
  const int ge  = l >> 2;
  const int gk0 = (l & 3) * 16;
  const int dg  = __shfl(d, ge);
  const int sg  = __shfl(s, ge);
  {
    const float4* pd = (const float4*)(Yd + (size_t)dg * DD + gk0);
    const float4* ps = (const float4*)(Ys + (size_t)sg * DD + gk0);
    float4 va[4], vb[4];
#pragma unroll
    for (int f = 0; f < 4; ++f) { va[f] = pd[f]; vb[f] = ps[f]; }
#pragma unroll
    for (int f = 0; f < 4; ++f) {
      float4 v = make_float4(relu(va[f].x + vb[f].x), relu(va[f].y + vb[f].y),
                             relu(va[f].z + vb[f].z), relu(va[f].w + vb[f].w));
      ushort4 h, lo;
      h.x = bfbits(v.x); lo.x = bfbits(v.x - bfval(h.x));
      h.y = bfbits(v.y); lo.y = bfbits(v.y - bfval(h.y));
      h.z = bfbits(v.z); lo.z = bfbits(v.z - bfval(h.z));
      h.w = bfbits(v.w); lo.w = bfbits(v.w - bfval(h.w));
      *(ushort4*)&h1[ge * SH + gk0 + f * 4] = h;
      *(ushort4*)&h1[16 * SH + ge * SH + gk0 + f * 4] = lo;
    }
  }

  const int mrow = l & 15;       // A row within the wave's 16-edge tile
  const int kq   = (l >> 4) * 8;
  const int cc   = l & 15;

  f32x4 acc[4];

  // ---- layer 1 (A = h1, B sec 2) -> h2 hi/lo
#pragma unroll
  for (int j = 0; j < 4; ++j) acc[j] = (f32x4){0.f, 0.f, 0.f, 0.f};
#pragma unroll
  for (int s2 = 0; s2 < 2; ++s2) {
    bf16x8 ah = ldfrag(&h1[mrow * SH + s2 * 32 + kq]);
    bf16x8 al = ldfrag(&h1[16 * SH + mrow * SH + s2 * 32 + kq]);
#pragma unroll
    for (int j = 0; j < 4; ++j) {
      const int fo = 2 * 4096 + ((j * 2 + s2) * 64 + l) * 8;
      bf16x8 bh = ldfrag(whi + fo);
      bf16x8 bl = ldfrag(wlo + fo);
      acc[j] = mfma16(al, bh, acc[j]);
      acc[j] = mfma16(ah, bl, acc[j]);
      acc[j] = mfma16(ah, bh, acc[j]);
    }
  }
#pragma unroll
  for (int j = 0; j < 4; ++j) {
    const int   c  = j * 16 + cc;
    const float bb = b1[c];
#pragma unroll
    for (int i = 0; i < 4; ++i) {
      const int r = (l >> 4) * 4 + i;   // rows 0..15 (C layout)
      float v = relu(acc[j][i] + bb);
      unsigned short hi = bfbits(v);
      h2[r * SH + c] = hi;
      h2[16 * SH + r * SH + c] = bfbits(v - bfval(hi));
    }
  }

  // ---- layer 2 (A = h2, B sec 3) -> msg fp32 (aliases h1; h1 reads done)
#pragma unroll
  for (int j = 0; j < 4; ++j) acc[j] = (f32x4){0.f, 0.f, 0.f, 0.f};
#pragma unroll
  for (int s2 = 0; s2 < 2; ++s2) {
    bf16x8 ah = ldfrag(&h2[mrow * SH + s2 * 32 + kq]);
    bf16x8 al = ldfrag(&h2[16 * SH + mrow * SH + s2 * 32 + kq]);
#pragma unroll
    for (int j = 0; j < 4; ++j) {
      const int fo = 3 * 4096 + ((j * 2 + s2) * 64 + l) * 8;
      bf16x8 bh = ldfrag(whi + fo);
      bf16x8 bl = ldfrag(wlo + fo);
      acc[j] = mfma16(al, bh, acc[j]);
      acc[j] = mfma16(ah, bl, acc[j]);
      acc[j] = mfma16(ah, bh, acc[j]);
    }
  }
#pragma unroll
  for (int j = 0; j < 4; ++j) {
    const int   c  = j * 16 + cc;
    const float bb = b2[c];
#pragma unroll
    for (int i = 0; i < 4; ++i) {
      const int r = (l >> 4) * 4 + i;
      msg[r * SH + c] = relu(acc[j][i] + bb);
    }
  }

  // ---- per-wave segmented reduction: lane owns column l, walk 16 rows.
  // Runs fully inside the window -> plain store (exclusive owner, global
  // dst-sort). First/last runs -> atomicAdd (may span window boundary).
  {
    int   cur   = __shfl(d, 0);
    float run   = 0.f;
    bool  first = true;
#pragma unroll
    for (int r = 0; r < 16; ++r) {
      float v  = msg[r * SH + l];
      int   dr = __shfl(d, r);          // wave-uniform
      if (r > 0 && dr != cur) {
        float* p = new_states + (size_t)cur * DD + l;
        if (first) atomicAdd(p, run);
        else       *p = run;
        first = false;
        run = 0.f;
        cur = dr;
      }
      run += v;
    }
    atomicAdd(new_states + (size_t)cur * DD + l, run);  // last run: conservative
  }
}

// ===========================================================================
// atom_kernel_v2: readout MFMA (fc1 sec 4, fc2 sec 5) + fp32 out + mol sum.
// ===========================================================================
__global__ __launch_bounds__(256, 4)
void atom_kernel_v2(const float* __restrict__ ns,
                    const unsigned short* __restrict__ whi,
                    const unsigned short* __restrict__ wlo,
                    const float* __restrict__ f1b,
                    const float* __restrict__ f2b,
                    const float* __restrict__ wo,
                    const float* __restrict__ bo,
                    float* __restrict__ out)
{
  __shared__ __align__(16) unsigned short Xb[2 * 64 * SH];
  __shared__ __align__(16) unsigned short Hb[2 * 64 * SH];
  unsigned short* Xh = Xb;
  unsigned short* Xl = Xb + 64 * SH;
  unsigned short* Hh = Hb;
  unsigned short* Hl = Hb + 64 * SH;
  float* h2f = (float*)Xb;    // 64 x SH floats fits (aliases Xb)
  float* oS  = (float*)Hb;

  const int t  = threadIdx.x;
  const int a0 = blockIdx.x * 64;

  {
    const int r  = t >> 2;
    const int k0 = (t & 3) * 16;
    const float4* s4 = (const float4*)(ns + (size_t)(a0 + r) * DD + k0);
#pragma unroll
    for (int f = 0; f < 4; ++f) {
      float4 v = s4[f];
      ushort4 h, lo;
      h.x = bfbits(v.x); lo.x = bfbits(v.x - bfval(h.x));
      h.y = bfbits(v.y); lo.y = bfbits(v.y - bfval(h.y));
      h.z = bfbits(v.z); lo.z = bfbits(v.z - bfval(h.z));
      h.w = bfbits(v.w); lo.w = bfbits(v.w - bfval(h.w));
      *(ushort4*)&Xh[r * SH + k0 + f * 4] = h;
      *(ushort4*)&Xl[r * SH + k0 + f * 4] = lo;
    }
  }

  const int l    = t & 63;
  const int w    = t >> 6;
  const int mrow = w * 16 + (l & 15);
  const int kq   = (l >> 4) * 8;
  const int cc   = l & 15;

  f32x4 acc[4];

#pragma unroll
  for (int j = 0; j < 4; ++j) acc[j] = (f32x4){0.f, 0.f, 0.f, 0.f};
#pragma unroll
  for (int s = 0; s < 2; ++s) {
    bf16x8 ah = ldfrag(&Xh[mrow * SH + s * 32 + kq]);
    bf16x8 al = ldfrag(&Xl[mrow * SH + s * 32 + kq]);
#pragma unroll
    for (int j = 0; j < 4; ++j) {
      const int fo = 4 * 4096 + ((j * 2 + s) * 64 + l) * 8;
      bf16x8 bh = ldfrag(whi + fo);
      bf16x8 bl = ldfrag(wlo + fo);
      acc[j] = mfma16(al, bh, acc[j]);
      acc[j] = mfma16(ah, bl, acc[j]);
      acc[j] = mfma16(ah, bh, acc[j]);
    }
  }
#pragma unroll
  for (int j = 0; j < 4; ++j) {
    const int   c  = j * 16 + cc;
    const float bb = f1b[c];
#pragma unroll
    for (int i = 0; i < 4; ++i) {
      const int r = w * 16 + (l >> 4) * 4 + i;
      float v = relu(acc[j][i] + bb);
      unsigned short hi = bfbits(v);
      Hh[r * SH + c] = hi;
      Hl[r * SH + c] = bfbits(v - bfval(hi));
    }
  }
  __syncthreads();

#pragma unroll
  for (int j = 0; j < 4; ++j) acc[j] = (f32x4){0.f, 0.f, 0.f, 0.f};
#pragma unroll
  for (int s = 0; s < 2; ++s) {
    bf16x8 ah = ldfrag(&Hh[mrow * SH + s * 32 + kq]);
    bf16x8 al = ldfrag(&Hl[mrow * SH + s * 32 + kq]);
#pragma unroll
    for (int j = 0; j < 4; ++j) {
      const int fo = 5 * 4096 + ((j * 2 + s) * 64 + l) * 8;
      bf16x8 bh = ldfrag(whi + fo);
      bf16x8 bl = ldfrag(wlo + fo);
      acc[j] = mfma16(al, bh, acc[j]);
      acc[j] = mfma16(ah, bl, acc[j]);
      acc[j] = mfma16(ah, bh, acc[j]);
    }
  }
#pragma unroll
  for (int j = 0; j < 4; ++j) {
    const int   c  = j * 16 + cc;
    const float bb = f2b[c];
#pragma unroll
    for (int i = 0; i < 4; ++i) {
      const int r = w * 16 + (l >> 4) * 4 + i;
      h2f[r * SH + c] = relu(acc[j][i] + bb);
    }
  }
  __syncthreads();

  {
    const int r  = t >> 2;
    const int c4 = (t & 3) * 4;
    float o4[4] = {0.f, 0.f, 0.f, 0.f};
#pragma unroll 8
    for (int k = 0; k < 64; ++k) {
      const float a = h2f[r * SH + k];
      float4 bw = *(const float4*)&wo[k * OUTD + c4];
      o4[0] += a * bw.x; o4[1] += a * bw.y; o4[2] += a * bw.z; o4[3] += a * bw.w;
    }
#pragma unroll
    for (int j = 0; j < 4; ++j)
      oS[r * 17 + c4 + j] = relu(o4[j] + bo[c4 + j]);
  }
  __syncthreads();

  if (t < 32) {
    const int m = t >> 4;
    const int c = t & 15;
    float s = 0.f;
#pragma unroll
    for (int a = 0; a < 32; ++a) s += oS[(m * 32 + a) * 17 + c];
    out[(blockIdx.x * 2 + m) * OUTD + c] = s;
  }
}

// ===========================================================================
extern "C" void kernel_launch(void* const* d_in, const int* in_sizes, int n_in,
                              void* d_out, int out_size, void* d_ws, size_t ws_size,
                              hipStream_t stream) {
  const float* atom_states = (const float*)d_in[0];
  const int*   edge_src    = (const int*)d_in[1];
  const int*   edge_dst    = (const int*)d_in[2];
  const float* ms0_w = (const float*)d_in[4];
  const float* ms0_b = (const float*)d_in[5];
  const float* ms1_w = (const float*)d_in[6];
  const float* ms1_b = (const float*)d_in[7];
  const float* ms2_w = (const float*)d_in[8];
  const float* ms2_b = (const float*)d_in[9];
  const float* fc1_w = (const float*)d_in[10];
  const float* fc1_b = (const float*)d_in[11];
  const float* fc2_w = (const float*)d_in[12];
  const float* fc2_b = (const float*)d_in[13];
  const float* out_w = (const float*)d_in[14];
  const float* out_b = (const float*)d_in[15];

  // ws layout (~101 MiB; proven available — R4/R5 ran this path)
  char* ws = (char*)d_ws;
  float* new_states = (float*)ws;
  size_t off = (size_t)N_ATOMS * DD * sizeof(float);                   // 32 MiB
  int* eids     = (int*)(ws + off); off += (size_t)N_EDGES * 4;        // +4 MiB
  int* counters = (int*)(ws + off); off += (size_t)N_ATOMS * 4;        // +512 KiB
  int* cursor   = (int*)(ws + off); off += (size_t)N_ATOMS * 4;        // +512 KiB
  int* partial  = (int*)(ws + off); off += 4096;                       // +4 KiB
  unsigned short* whi = (unsigned short*)(ws + off); off += 24576 * 2; // +48 KiB
  unsigned short* wlo = (unsigned short*)(ws + off); off += 24576 * 2; // +48 KiB
  float* Yd = (float*)(ws + off); off += (size_t)N_ATOMS * DD * sizeof(float);
  float* Ys = (float*)(ws + off); off += (size_t)N_ATOMS * DD * sizeof(float);

  void* cargs[] = {
    (void*)&atom_states, (void*)&edge_dst,
    (void*)&ms0_w, (void*)&ms1_w, (void*)&ms2_w, (void*)&fc1_w, (void*)&fc2_w,
    (void*)&ms0_b,
    (void*)&whi, (void*)&wlo,
    (void*)&counters, (void*)&cursor, (void*)&partial, (void*)&eids,
    (void*)&new_states, (void*)&Yd, (void*)&Ys
  };
  hipLaunchCooperativeKernel((void*)coop_prep, dim3(CBLK), dim3(256),
                             cargs, 0, stream);

  edge_kernel_v4<<<N_EDGES / 64, 256, 0, stream>>>(
      Yd, Ys, edge_src, edge_dst, eids, whi, wlo, ms1_b, ms2_b, new_states);

  atom_kernel_v2<<<N_ATOMS / 64, 256, 0, stream>>>(
      new_states, whi, wlo, fc1_b, fc2_b, out_w, out_b, (float*)d_out);
}

// Round 7
// 404.526 us; speedup vs baseline: 1.8568x; 1.8568x over previous
//
#include <hip/hip_runtime.h>

// MessagePassingNet on MI355X — Round 7:
//   * R6 lesson: cooperative grid.sync fusion = 465 µs of idle. Reverted.
//     Fusion now only for INDEPENDENT phases (block-range partitioning);
//     dependent phases are separate launches (stream is the sync). 7 dispatches.
//   * edge kernel: wave-autonomous barrier-free (R6 v4) + direct (dst,src)
//     sorted int2 array from scatter — no eids->edge_dst/src random hop.
//   * split-bf16 (hi/lo, 3-MFMA) everywhere; layer-0 hoisted per-atom.

constexpr int N_ATOMS = 131072;
constexpr int N_EDGES = 1048576;
constexpr int DD      = 64;
constexpr int OUTD    = 16;
constexpr int SH      = 72;   // halfword row stride for 64-wide hi/lo tiles

typedef __bf16 bf16x8 __attribute__((ext_vector_type(8)));
typedef float  f32x4  __attribute__((ext_vector_type(4)));

#define DEV_INLINE __device__ __forceinline__

DEV_INLINE float relu(float x) { return x > 0.f ? x : 0.f; }

DEV_INLINE unsigned short bfbits(float x) {
  __bf16 h = (__bf16)x;
  return __builtin_bit_cast(unsigned short, h);
}
DEV_INLINE float bfval(unsigned short u) {
  unsigned int v = ((unsigned int)u) << 16;
  return __builtin_bit_cast(float, v);
}
DEV_INLINE f32x4 mfma16(bf16x8 a, bf16x8 b, f32x4 c) {
  return __builtin_amdgcn_mfma_f32_16x16x32_bf16(a, b, c, 0, 0, 0);
}
DEV_INLINE bf16x8 ldfrag(const unsigned short* p) { return *(const bf16x8*)p; }

// ===========================================================================
// fused_k1: blocks [0,4096) histogram | [4096,6144) zero new_states |
//           [6144,6156) weight pack (hi/lo, B-fragment order).
// All three phases independent (counters pre-zeroed by memset).
// Weight sections: 0=W0 dst half, 1=W0 src half, 2=W1, 3=W2, 4=FC1, 5=FC2.
// fo(sec,j,s,l) = sec*4096 + ((j*2+s)*64 + l)*8
// ===========================================================================
__global__ __launch_bounds__(256, 4)
void fused_k1(const int* __restrict__ edge_dst,
              const float* __restrict__ w0, const float* __restrict__ w1,
              const float* __restrict__ w2, const float* __restrict__ f1,
              const float* __restrict__ f2,
              int* __restrict__ counters,
              float* __restrict__ new_states,
              unsigned short* __restrict__ whi, unsigned short* __restrict__ wlo)
{
  const int t = threadIdx.x, b = blockIdx.x;

  if (b < 4096) {                       // histogram
    int i = b * 256 + t;
    atomicAdd(&counters[edge_dst[i]], 1);
  } else if (b < 6144) {                // zero new_states (32 MiB)
    float4* ns4 = (float4*)new_states;
    const int n4 = N_ATOMS * DD / 4;
    for (int i = (b - 4096) * 256 + t; i < n4; i += 2048 * 256)
      ns4[i] = make_float4(0.f, 0.f, 0.f, 0.f);
  } else {                              // weight pack (3072 threads)
    int tid = (b - 6144) * 256 + t;
    int sec = tid >> 9, rel = tid & 511;
    const float* w; int rowoff = 0;
    switch (sec) {
      case 0: w = w0; rowoff = 0;  break;
      case 1: w = w0; rowoff = 64; break;
      case 2: w = w1; break;
      case 3: w = w2; break;
      case 4: w = f1; break;
      default: w = f2; break;
    }
    const int tile = rel >> 6, lane = rel & 63;
    const int j = tile >> 1, s = tile & 1;
    const int n  = j * 16 + (lane & 15);
    const int kb = s * 32 + (lane >> 4) * 8;
    const int out = sec * 4096 + (tile * 64 + lane) * 8;
#pragma unroll
    for (int i = 0; i < 8; ++i) {
      float v = w[(rowoff + kb + i) * 64 + n];
      unsigned short h = bfbits(v);
      whi[out + i] = h;
      wlo[out + i] = bfbits(v - bfval(h));
    }
  }
}

// ===========================================================================
// blocksum + merged scanwrite (proven R5)
// ===========================================================================
__global__ void blocksum_kernel(const int* __restrict__ counters,
                                int* __restrict__ partial) {
  __shared__ int s[256];
  int t = threadIdx.x;
  s[t] = counters[blockIdx.x * 256 + t];
  __syncthreads();
  for (int off = 128; off > 0; off >>= 1) {
    if (t < off) s[t] += s[t + off];
    __syncthreads();
  }
  if (t == 0) partial[blockIdx.x] = s[0];
}

__global__ void scanwrite_kernel(const int* __restrict__ counters,
                                 const int* __restrict__ partial,
                                 int* __restrict__ cursor) {
  __shared__ int s[256];
  __shared__ int pS[256];
  int t = threadIdx.x, b = blockIdx.x;

  int acc = 0;
  int p0 = partial[t];       if (t < b)       acc += p0;
  int p1 = partial[256 + t]; if (256 + t < b) acc += p1;
  pS[t] = acc;
  __syncthreads();
  for (int off = 128; off > 0; off >>= 1) {
    if (t < off) pS[t] += pS[t + off];
    __syncthreads();
  }
  const int base = pS[0];

  int v = counters[b * 256 + t];
  s[t] = v;
  __syncthreads();
  for (int off = 1; off < 256; off <<= 1) {
    int x = (t >= off) ? s[t - off] : 0;
    __syncthreads();
    s[t] += x;
    __syncthreads();
  }
  cursor[b * 256 + t] = base + s[t] - v;  // exclusive
}

// ===========================================================================
// fused_k2: blocks [0,4096) scatter | [4096,6144) atom_pre (64 atoms each).
// Scatter writes sorted (dst,src) int2 (use_ds=1) or eids (use_ds=0).
// atom_pre: Yd = X*W0d + b0, Ys = X*W0s (split-bf16 MFMA, band-local, no barrier).
// ===========================================================================
__global__ __launch_bounds__(256, 4)
void fused_k2(const float* __restrict__ atom_states,
              const int* __restrict__ edge_src,
              const int* __restrict__ edge_dst,
              int* __restrict__ cursor,
              int2* __restrict__ ds_sorted,
              int* __restrict__ eids,
              int use_ds,
              const unsigned short* __restrict__ whi,
              const unsigned short* __restrict__ wlo,
              const float* __restrict__ b0,
              float* __restrict__ Yd, float* __restrict__ Ys)
{
  __shared__ __align__(16) unsigned short Xh[64 * SH];
  __shared__ __align__(16) unsigned short Xl[64 * SH];

  const int t = threadIdx.x, b = blockIdx.x;

  if (b < 4096) {                       // scatter
    int i = b * 256 + t;
    int d = edge_dst[i];
    int pos = atomicAdd(&cursor[d], 1);
    if (use_ds) ds_sorted[pos] = make_int2(d, edge_src[i]);
    else        eids[pos] = i;
    return;
  }

  // ---- atom_pre ----
  const int a0 = (b - 4096) * 64;
  {
    const int r  = t >> 2;
    const int k0 = (t & 3) * 16;
    const float4* s4 = (const float4*)(atom_states + (size_t)(a0 + r) * DD + k0);
#pragma unroll
    for (int f = 0; f < 4; ++f) {
      float4 v = s4[f];
      ushort4 h, lo;
      h.x = bfbits(v.x); lo.x = bfbits(v.x - bfval(h.x));
      h.y = bfbits(v.y); lo.y = bfbits(v.y - bfval(h.y));
      h.z = bfbits(v.z); lo.z = bfbits(v.z - bfval(h.z));
      h.w = bfbits(v.w); lo.w = bfbits(v.w - bfval(h.w));
      *(ushort4*)&Xh[r * SH + k0 + f * 4] = h;
      *(ushort4*)&Xl[r * SH + k0 + f * 4] = lo;
    }
  }

  const int l    = t & 63;
  const int w    = t >> 6;
  const int mrow = w * 16 + (l & 15);
  const int kq   = (l >> 4) * 8;
  const int cc   = l & 15;

#pragma unroll
  for (int side = 0; side < 2; ++side) {
    f32x4 acc[4];
#pragma unroll
    for (int j = 0; j < 4; ++j) acc[j] = (f32x4){0.f, 0.f, 0.f, 0.f};
#pragma unroll
    for (int s = 0; s < 2; ++s) {
      bf16x8 ah = ldfrag(&Xh[mrow * SH + s * 32 + kq]);
      bf16x8 al = ldfrag(&Xl[mrow * SH + s * 32 + kq]);
#pragma unroll
      for (int j = 0; j < 4; ++j) {
        const int fo = side * 4096 + ((j * 2 + s) * 64 + l) * 8;
        bf16x8 bh = ldfrag(whi + fo);
        bf16x8 bl = ldfrag(wlo + fo);
        acc[j] = mfma16(al, bh, acc[j]);
        acc[j] = mfma16(ah, bl, acc[j]);
        acc[j] = mfma16(ah, bh, acc[j]);
      }
    }
    float* Y = side ? Ys : Yd;
#pragma unroll
    for (int j = 0; j < 4; ++j) {
      const int   c  = j * 16 + cc;
      const float bb = side ? 0.f : b0[c];
#pragma unroll
      for (int i = 0; i < 4; ++i) {
        const int r = w * 16 + (l >> 4) * 4 + i;
        Y[(size_t)(a0 + r) * DD + c] = acc[j][i] + bb;
      }
    }
  }
}

// ===========================================================================
// edge_kernel_v5: wave-autonomous, barrier-free (R6 v4 structure).
// Index fetch: one coalesced int2 load (use_ds) or eids->dst/src hop.
// Per wave: 16 dst-sorted edges, own LDS slice, 16x64 split-bf16 GEMMs,
// per-wave segmented reduction (interior runs store, boundary runs atomic).
// ===========================================================================
__global__ __launch_bounds__(256, 4)
void edge_kernel_v5(const float* __restrict__ Yd,
                    const float* __restrict__ Ys,
                    const int2* __restrict__ ds_sorted,
                    const int* __restrict__ eids,
                    const int* __restrict__ edge_src,
                    const int* __restrict__ edge_dst,
                    int use_ds,
                    const unsigned short* __restrict__ whi,
                    const unsigned short* __restrict__ wlo,
                    const float* __restrict__ b1,
                    const float* __restrict__ b2,
                    float* __restrict__ new_states)
{
  __shared__ __align__(16) unsigned short H1[4][2 * 16 * SH];
  __shared__ __align__(16) unsigned short H2[4][2 * 16 * SH];

  const int t = threadIdx.x;
  const int w = t >> 6;
  const int l = t & 63;
  const int e0 = blockIdx.x * 64 + w * 16;

  unsigned short* h1 = H1[w];            // hi at 0, lo at 16*SH
  unsigned short* h2 = H2[w];
  float* msg = (float*)H1[w];

  // ---- per-lane index load (lanes 0..15 hold this wave's 16 edges)
  int d = 0, s = 0;
  if (l < 16) {
    if (use_ds) {
      int2 ds = ds_sorted[e0 + l];
      d = ds.x; s = ds.y;
    } else {
      int eid = eids[e0 + l];
      d = edge_dst[eid];
      s = edge_src[eid];
    }
  }

  // ---- gather h1 = relu(Yd[dst] + Ys[src]), hi/lo split (4 lanes/edge)
  const int ge  = l >> 2;
  const int gk0 = (l & 3) * 16;
  const int dg  = __shfl(d, ge);
  const int sg  = __shfl(s, ge);
  {
    const float4* pd = (const float4*)(Yd + (size_t)dg * DD + gk0);
    const float4* ps = (const float4*)(Ys + (size_t)sg * DD + gk0);
    float4 va[4], vb[4];
#pragma unroll
    for (int f = 0; f < 4; ++f) { va[f] = pd[f]; vb[f] = ps[f]; }
#pragma unroll
    for (int f = 0; f < 4; ++f) {
      float4 v = make_float4(relu(va[f].x + vb[f].x), relu(va[f].y + vb[f].y),
                             relu(va[f].z + vb[f].z), relu(va[f].w + vb[f].w));
      ushort4 h, lo;
      h.x = bfbits(v.x); lo.x = bfbits(v.x - bfval(h.x));
      h.y = bfbits(v.y); lo.y = bfbits(v.y - bfval(h.y));
      h.z = bfbits(v.z); lo.z = bfbits(v.z - bfval(h.z));
      h.w = bfbits(v.w); lo.w = bfbits(v.w - bfval(h.w));
      *(ushort4*)&h1[ge * SH + gk0 + f * 4] = h;
      *(ushort4*)&h1[16 * SH + ge * SH + gk0 + f * 4] = lo;
    }
  }

  const int mrow = l & 15;
  const int kq   = (l >> 4) * 8;
  const int cc   = l & 15;

  f32x4 acc[4];

  // ---- layer 1 (A = h1, B sec 2) -> h2 hi/lo
#pragma unroll
  for (int j = 0; j < 4; ++j) acc[j] = (f32x4){0.f, 0.f, 0.f, 0.f};
#pragma unroll
  for (int s2 = 0; s2 < 2; ++s2) {
    bf16x8 ah = ldfrag(&h1[mrow * SH + s2 * 32 + kq]);
    bf16x8 al = ldfrag(&h1[16 * SH + mrow * SH + s2 * 32 + kq]);
#pragma unroll
    for (int j = 0; j < 4; ++j) {
      const int fo = 2 * 4096 + ((j * 2 + s2) * 64 + l) * 8;
      bf16x8 bh = ldfrag(whi + fo);
      bf16x8 bl = ldfrag(wlo + fo);
      acc[j] = mfma16(al, bh, acc[j]);
      acc[j] = mfma16(ah, bl, acc[j]);
      acc[j] = mfma16(ah, bh, acc[j]);
    }
  }
#pragma unroll
  for (int j = 0; j < 4; ++j) {
    const int   c  = j * 16 + cc;
    const float bb = b1[c];
#pragma unroll
    for (int i = 0; i < 4; ++i) {
      const int r = (l >> 4) * 4 + i;
      float v = relu(acc[j][i] + bb);
      unsigned short hi = bfbits(v);
      h2[r * SH + c] = hi;
      h2[16 * SH + r * SH + c] = bfbits(v - bfval(hi));
    }
  }

  // ---- layer 2 (A = h2, B sec 3) -> msg fp32 (aliases h1; same-wave order)
#pragma unroll
  for (int j = 0; j < 4; ++j) acc[j] = (f32x4){0.f, 0.f, 0.f, 0.f};
#pragma unroll
  for (int s2 = 0; s2 < 2; ++s2) {
    bf16x8 ah = ldfrag(&h2[mrow * SH + s2 * 32 + kq]);
    bf16x8 al = ldfrag(&h2[16 * SH + mrow * SH + s2 * 32 + kq]);
#pragma unroll
    for (int j = 0; j < 4; ++j) {
      const int fo = 3 * 4096 + ((j * 2 + s2) * 64 + l) * 8;
      bf16x8 bh = ldfrag(whi + fo);
      bf16x8 bl = ldfrag(wlo + fo);
      acc[j] = mfma16(al, bh, acc[j]);
      acc[j] = mfma16(ah, bl, acc[j]);
      acc[j] = mfma16(ah, bh, acc[j]);
    }
  }
#pragma unroll
  for (int j = 0; j < 4; ++j) {
    const int   c  = j * 16 + cc;
    const float bb = b2[c];
#pragma unroll
    for (int i = 0; i < 4; ++i) {
      const int r = (l >> 4) * 4 + i;
      msg[r * SH + c] = relu(acc[j][i] + bb);
    }
  }

  // ---- per-wave segmented reduction: lane owns column l, walks 16 rows.
  {
    int   cur   = __shfl(d, 0);
    float run   = 0.f;
    bool  first = true;
#pragma unroll
    for (int r = 0; r < 16; ++r) {
      float v  = msg[r * SH + l];
      int   dr = __shfl(d, r);          // wave-uniform
      if (r > 0 && dr != cur) {
        float* p = new_states + (size_t)cur * DD + l;
        if (first) atomicAdd(p, run);
        else       *p = run;            // interior run: exclusive owner
        first = false;
        run = 0.f;
        cur = dr;
      }
      run += v;
    }
    atomicAdd(new_states + (size_t)cur * DD + l, run);  // last run
  }
}

// ===========================================================================
// atom_kernel_v2: readout MFMA (fc1 sec 4, fc2 sec 5) + fp32 out + mol sum.
// ===========================================================================
__global__ __launch_bounds__(256, 4)
void atom_kernel_v2(const float* __restrict__ ns,
                    const unsigned short* __restrict__ whi,
                    const unsigned short* __restrict__ wlo,
                    const float* __restrict__ f1b,
                    const float* __restrict__ f2b,
                    const float* __restrict__ wo,
                    const float* __restrict__ bo,
                    float* __restrict__ out)
{
  __shared__ __align__(16) unsigned short Xb[2 * 64 * SH];
  __shared__ __align__(16) unsigned short Hb[2 * 64 * SH];
  unsigned short* Xh = Xb;
  unsigned short* Xl = Xb + 64 * SH;
  unsigned short* Hh = Hb;
  unsigned short* Hl = Hb + 64 * SH;
  float* h2f = (float*)Xb;
  float* oS  = (float*)Hb;

  const int t  = threadIdx.x;
  const int a0 = blockIdx.x * 64;

  {
    const int r  = t >> 2;
    const int k0 = (t & 3) * 16;
    const float4* s4 = (const float4*)(ns + (size_t)(a0 + r) * DD + k0);
#pragma unroll
    for (int f = 0; f < 4; ++f) {
      float4 v = s4[f];
      ushort4 h, lo;
      h.x = bfbits(v.x); lo.x = bfbits(v.x - bfval(h.x));
      h.y = bfbits(v.y); lo.y = bfbits(v.y - bfval(h.y));
      h.z = bfbits(v.z); lo.z = bfbits(v.z - bfval(h.z));
      h.w = bfbits(v.w); lo.w = bfbits(v.w - bfval(h.w));
      *(ushort4*)&Xh[r * SH + k0 + f * 4] = h;
      *(ushort4*)&Xl[r * SH + k0 + f * 4] = lo;
    }
  }

  const int l    = t & 63;
  const int w    = t >> 6;
  const int mrow = w * 16 + (l & 15);
  const int kq   = (l >> 4) * 8;
  const int cc   = l & 15;

  f32x4 acc[4];

#pragma unroll
  for (int j = 0; j < 4; ++j) acc[j] = (f32x4){0.f, 0.f, 0.f, 0.f};
#pragma unroll
  for (int s = 0; s < 2; ++s) {
    bf16x8 ah = ldfrag(&Xh[mrow * SH + s * 32 + kq]);
    bf16x8 al = ldfrag(&Xl[mrow * SH + s * 32 + kq]);
#pragma unroll
    for (int j = 0; j < 4; ++j) {
      const int fo = 4 * 4096 + ((j * 2 + s) * 64 + l) * 8;
      bf16x8 bh = ldfrag(whi + fo);
      bf16x8 bl = ldfrag(wlo + fo);
      acc[j] = mfma16(al, bh, acc[j]);
      acc[j] = mfma16(ah, bl, acc[j]);
      acc[j] = mfma16(ah, bh, acc[j]);
    }
  }
#pragma unroll
  for (int j = 0; j < 4; ++j) {
    const int   c  = j * 16 + cc;
    const float bb = f1b[c];
#pragma unroll
    for (int i = 0; i < 4; ++i) {
      const int r = w * 16 + (l >> 4) * 4 + i;
      float v = relu(acc[j][i] + bb);
      unsigned short hi = bfbits(v);
      Hh[r * SH + c] = hi;
      Hl[r * SH + c] = bfbits(v - bfval(hi));
    }
  }
  __syncthreads();

#pragma unroll
  for (int j = 0; j < 4; ++j) acc[j] = (f32x4){0.f, 0.f, 0.f, 0.f};
#pragma unroll
  for (int s = 0; s < 2; ++s) {
    bf16x8 ah = ldfrag(&Hh[mrow * SH + s * 32 + kq]);
    bf16x8 al = ldfrag(&Hl[mrow * SH + s * 32 + kq]);
#pragma unroll
    for (int j = 0; j < 4; ++j) {
      const int fo = 5 * 4096 + ((j * 2 + s) * 64 + l) * 8;
      bf16x8 bh = ldfrag(whi + fo);
      bf16x8 bl = ldfrag(wlo + fo);
      acc[j] = mfma16(al, bh, acc[j]);
      acc[j] = mfma16(ah, bl, acc[j]);
      acc[j] = mfma16(ah, bh, acc[j]);
    }
  }
#pragma unroll
  for (int j = 0; j < 4; ++j) {
    const int   c  = j * 16 + cc;
    const float bb = f2b[c];
#pragma unroll
    for (int i = 0; i < 4; ++i) {
      const int r = w * 16 + (l >> 4) * 4 + i;
      h2f[r * SH + c] = relu(acc[j][i] + bb);
    }
  }
  __syncthreads();

  {
    const int r  = t >> 2;
    const int c4 = (t & 3) * 4;
    float o4[4] = {0.f, 0.f, 0.f, 0.f};
#pragma unroll 8
    for (int k = 0; k < 64; ++k) {
      const float a = h2f[r * SH + k];
      float4 bw = *(const float4*)&wo[k * OUTD + c4];
      o4[0] += a * bw.x; o4[1] += a * bw.y; o4[2] += a * bw.z; o4[3] += a * bw.w;
    }
#pragma unroll
    for (int j = 0; j < 4; ++j)
      oS[r * 17 + c4 + j] = relu(o4[j] + bo[c4 + j]);
  }
  __syncthreads();

  if (t < 32) {
    const int m = t >> 4;
    const int c = t & 15;
    float s = 0.f;
#pragma unroll
    for (int a = 0; a < 32; ++a) s += oS[(m * 32 + a) * 17 + c];
    out[(blockIdx.x * 2 + m) * OUTD + c] = s;
  }
}

// ===========================================================================
extern "C" void kernel_launch(void* const* d_in, const int* in_sizes, int n_in,
                              void* d_out, int out_size, void* d_ws, size_t ws_size,
                              hipStream_t stream) {
  const float* atom_states = (const float*)d_in[0];
  const int*   edge_src    = (const int*)d_in[1];
  const int*   edge_dst    = (const int*)d_in[2];
  const float* ms0_w = (const float*)d_in[4];
  const float* ms0_b = (const float*)d_in[5];
  const float* ms1_w = (const float*)d_in[6];
  const float* ms1_b = (const float*)d_in[7];
  const float* ms2_w = (const float*)d_in[8];
  const float* ms2_b = (const float*)d_in[9];
  const float* fc1_w = (const float*)d_in[10];
  const float* fc1_b = (const float*)d_in[11];
  const float* fc2_w = (const float*)d_in[12];
  const float* fc2_b = (const float*)d_in[13];
  const float* out_w = (const float*)d_in[14];
  const float* out_b = (const float*)d_in[15];

  // ws layout: base (R4-proven ~101 MiB) + optional ds_sorted (8 MiB) at tail
  char* ws = (char*)d_ws;
  float* new_states = (float*)ws;
  size_t off = (size_t)N_ATOMS * DD * sizeof(float);                   // 32 MiB
  int* eids     = (int*)(ws + off); off += (size_t)N_EDGES * 4;        // +4 MiB
  int* counters = (int*)(ws + off); off += (size_t)N_ATOMS * 4;        // +512 KiB
  int* cursor   = (int*)(ws + off); off += (size_t)N_ATOMS * 4;        // +512 KiB
  int* partial  = (int*)(ws + off); off += 4096;                       // +4 KiB
  unsigned short* whi = (unsigned short*)(ws + off); off += 24576 * 2; // +48 KiB
  unsigned short* wlo = (unsigned short*)(ws + off); off += 24576 * 2; // +48 KiB
  float* Yd = (float*)(ws + off); off += (size_t)N_ATOMS * DD * sizeof(float);
  float* Ys = (float*)(ws + off); off += (size_t)N_ATOMS * DD * sizeof(float);
  int2* ds_sorted = (int2*)(ws + off);
  const size_t need_ds = off + (size_t)N_EDGES * sizeof(int2);         // ~109 MiB
  const int use_ds = (ws_size >= need_ds) ? 1 : 0;   // constant across calls

  hipMemsetAsync(counters, 0, (size_t)N_ATOMS * 4, stream);

  fused_k1<<<6156, 256, 0, stream>>>(edge_dst, ms0_w, ms1_w, ms2_w, fc1_w, fc2_w,
                                     counters, new_states, whi, wlo);
  blocksum_kernel<<<512, 256, 0, stream>>>(counters, partial);
  scanwrite_kernel<<<512, 256, 0, stream>>>(counters, partial, cursor);
  fused_k2<<<6144, 256, 0, stream>>>(atom_states, edge_src, edge_dst, cursor,
                                     ds_sorted, eids, use_ds,
                                     whi, wlo, ms0_b, Yd, Ys);
  edge_kernel_v5<<<N_EDGES / 64, 256, 0, stream>>>(
      Yd, Ys, ds_sorted, eids, edge_src, edge_dst, use_ds,
      whi, wlo, ms1_b, ms2_b, new_states);
  atom_kernel_v2<<<N_ATOMS / 64, 256, 0, stream>>>(
      new_states, whi, wlo, fc1_b, fc2_b, out_w, out_b, (float*)d_out);
}

// Round 8
// 402.301 us; speedup vs baseline: 1.8671x; 1.0055x over previous
//
#include <hip/hip_runtime.h>

// MessagePassingNet on MI355X — Round 8:
//   * edge kernel v6: gather straight into MFMA A-fragments (registers) —
//     h1 never touches LDS. LDS/WG 36.9 -> 18.4 KB => LDS cap 4 -> 8 WGs/CU.
//   * atom_pre: same register-A-fragment trick, zero LDS.
//   * pipeline otherwise as R7 (independent-phase fusion, 7 dispatches,
//     ds_sorted int2, wave-autonomous barrier-free edge kernel).

constexpr int N_ATOMS = 131072;
constexpr int N_EDGES = 1048576;
constexpr int DD      = 64;
constexpr int OUTD    = 16;
constexpr int SH      = 72;   // halfword row stride for 64-wide hi/lo tiles

typedef __bf16 bf16x8 __attribute__((ext_vector_type(8)));
typedef float  f32x4  __attribute__((ext_vector_type(4)));
typedef unsigned short u16x8 __attribute__((ext_vector_type(8)));

#define DEV_INLINE __device__ __forceinline__

DEV_INLINE float relu(float x) { return x > 0.f ? x : 0.f; }

DEV_INLINE unsigned short bfbits(float x) {
  __bf16 h = (__bf16)x;
  return __builtin_bit_cast(unsigned short, h);
}
DEV_INLINE float bfval(unsigned short u) {
  unsigned int v = ((unsigned int)u) << 16;
  return __builtin_bit_cast(float, v);
}
DEV_INLINE f32x4 mfma16(bf16x8 a, bf16x8 b, f32x4 c) {
  return __builtin_amdgcn_mfma_f32_16x16x32_bf16(a, b, c, 0, 0, 0);
}
DEV_INLINE bf16x8 ldfrag(const unsigned short* p) { return *(const bf16x8*)p; }

// split 8 floats (two float4) into bf16 hi/lo A-fragments
DEV_INLINE void mk_frag(float4 a0, float4 a1, bf16x8& fh, bf16x8& fl) {
  const float v[8] = {a0.x, a0.y, a0.z, a0.w, a1.x, a1.y, a1.z, a1.w};
  u16x8 hh, ll;
#pragma unroll
  for (int i = 0; i < 8; ++i) {
    unsigned short h = bfbits(v[i]);
    hh[i] = h;
    ll[i] = bfbits(v[i] - bfval(h));
  }
  fh = __builtin_bit_cast(bf16x8, hh);
  fl = __builtin_bit_cast(bf16x8, ll);
}

// ===========================================================================
// fused_k1: [0,4096) histogram | [4096,6144) zero new_states | [6144,6156)
// weight pack. Sections: 0=W0d 1=W0s 2=W1 3=W2 4=FC1 5=FC2.
// fo(sec,j,s,l) = sec*4096 + ((j*2+s)*64 + l)*8
// ===========================================================================
__global__ __launch_bounds__(256, 4)
void fused_k1(const int* __restrict__ edge_dst,
              const float* __restrict__ w0, const float* __restrict__ w1,
              const float* __restrict__ w2, const float* __restrict__ f1,
              const float* __restrict__ f2,
              int* __restrict__ counters,
              float* __restrict__ new_states,
              unsigned short* __restrict__ whi, unsigned short* __restrict__ wlo)
{
  const int t = threadIdx.x, b = blockIdx.x;

  if (b < 4096) {
    int i = b * 256 + t;
    atomicAdd(&counters[edge_dst[i]], 1);
  } else if (b < 6144) {
    float4* ns4 = (float4*)new_states;
    const int n4 = N_ATOMS * DD / 4;
    for (int i = (b - 4096) * 256 + t; i < n4; i += 2048 * 256)
      ns4[i] = make_float4(0.f, 0.f, 0.f, 0.f);
  } else {
    int tid = (b - 6144) * 256 + t;
    int sec = tid >> 9, rel = tid & 511;
    const float* w; int rowoff = 0;
    switch (sec) {
      case 0: w = w0; rowoff = 0;  break;
      case 1: w = w0; rowoff = 64; break;
      case 2: w = w1; break;
      case 3: w = w2; break;
      case 4: w = f1; break;
      default: w = f2; break;
    }
    const int tile = rel >> 6, lane = rel & 63;
    const int j = tile >> 1, s = tile & 1;
    const int n  = j * 16 + (lane & 15);
    const int kb = s * 32 + (lane >> 4) * 8;
    const int out = sec * 4096 + (tile * 64 + lane) * 8;
#pragma unroll
    for (int i = 0; i < 8; ++i) {
      float v = w[(rowoff + kb + i) * 64 + n];
      unsigned short h = bfbits(v);
      whi[out + i] = h;
      wlo[out + i] = bfbits(v - bfval(h));
    }
  }
}

// ===========================================================================
__global__ void blocksum_kernel(const int* __restrict__ counters,
                                int* __restrict__ partial) {
  __shared__ int s[256];
  int t = threadIdx.x;
  s[t] = counters[blockIdx.x * 256 + t];
  __syncthreads();
  for (int off = 128; off > 0; off >>= 1) {
    if (t < off) s[t] += s[t + off];
    __syncthreads();
  }
  if (t == 0) partial[blockIdx.x] = s[0];
}

__global__ void scanwrite_kernel(const int* __restrict__ counters,
                                 const int* __restrict__ partial,
                                 int* __restrict__ cursor) {
  __shared__ int s[256];
  __shared__ int pS[256];
  int t = threadIdx.x, b = blockIdx.x;

  int acc = 0;
  int p0 = partial[t];       if (t < b)       acc += p0;
  int p1 = partial[256 + t]; if (256 + t < b) acc += p1;
  pS[t] = acc;
  __syncthreads();
  for (int off = 128; off > 0; off >>= 1) {
    if (t < off) pS[t] += pS[t + off];
    __syncthreads();
  }
  const int base = pS[0];

  int v = counters[b * 256 + t];
  s[t] = v;
  __syncthreads();
  for (int off = 1; off < 256; off <<= 1) {
    int x = (t >= off) ? s[t - off] : 0;
    __syncthreads();
    s[t] += x;
    __syncthreads();
  }
  cursor[b * 256 + t] = base + s[t] - v;  // exclusive
}

// ===========================================================================
// fused_k2: [0,4096) scatter -> ds_sorted/eids | [4096,6144) atom_pre.
// atom_pre uses register A-fragments: ZERO LDS, zero barriers.
// ===========================================================================
__global__ __launch_bounds__(256, 4)
void fused_k2(const float* __restrict__ atom_states,
              const int* __restrict__ edge_src,
              const int* __restrict__ edge_dst,
              int* __restrict__ cursor,
              int2* __restrict__ ds_sorted,
              int* __restrict__ eids,
              int use_ds,
              const unsigned short* __restrict__ whi,
              const unsigned short* __restrict__ wlo,
              const float* __restrict__ b0,
              float* __restrict__ Yd, float* __restrict__ Ys)
{
  const int t = threadIdx.x, b = blockIdx.x;

  if (b < 4096) {                       // scatter
    int i = b * 256 + t;
    int d = edge_dst[i];
    int pos = atomicAdd(&cursor[d], 1);
    if (use_ds) ds_sorted[pos] = make_int2(d, edge_src[i]);
    else        eids[pos] = i;
    return;
  }

  // ---- atom_pre: wave w owns atoms a0 + w*16 + (l&15)
  const int a0 = (b - 4096) * 64;
  const int l  = t & 63;
  const int w  = t >> 6;
  const int fi = (l >> 4) * 2;          // float4 index within 32-float k-step
  const int cc = l & 15;
  const int arow = a0 + w * 16 + (l & 15);

  bf16x8 xh[2], xl[2];
  {
    const float4* px = (const float4*)(atom_states + (size_t)arow * DD);
#pragma unroll
    for (int s = 0; s < 2; ++s) {
      float4 x0 = px[s * 8 + fi], x1 = px[s * 8 + fi + 1];
      mk_frag(x0, x1, xh[s], xl[s]);
    }
  }

#pragma unroll
  for (int side = 0; side < 2; ++side) {
    f32x4 acc[4];
#pragma unroll
    for (int j = 0; j < 4; ++j) acc[j] = (f32x4){0.f, 0.f, 0.f, 0.f};
#pragma unroll
    for (int s = 0; s < 2; ++s) {
#pragma unroll
      for (int j = 0; j < 4; ++j) {
        const int fo = side * 4096 + ((j * 2 + s) * 64 + l) * 8;
        bf16x8 bh = ldfrag(whi + fo);
        bf16x8 bl = ldfrag(wlo + fo);
        acc[j] = mfma16(xl[s], bh, acc[j]);
        acc[j] = mfma16(xh[s], bl, acc[j]);
        acc[j] = mfma16(xh[s], bh, acc[j]);
      }
    }
    float* Y = side ? Ys : Yd;
#pragma unroll
    for (int j = 0; j < 4; ++j) {
      const int   c  = j * 16 + cc;
      const float bb = side ? 0.f : b0[c];
#pragma unroll
      for (int i = 0; i < 4; ++i) {
        const int r = w * 16 + (l >> 4) * 4 + i;
        Y[(size_t)(a0 + r) * DD + c] = acc[j][i] + bb;
      }
    }
  }
}

// ===========================================================================
// edge_kernel_v6: wave-autonomous, barrier-free. h1 gathered DIRECTLY into
// register A-fragments (lane q: rows of edge q&15 at its own k-offset).
// LDS = per-wave h2 transpose slice only (msg aliases it). 18.4 KB/WG.
// ===========================================================================
__global__ __launch_bounds__(256, 6)
void edge_kernel_v6(const float* __restrict__ Yd,
                    const float* __restrict__ Ys,
                    const int2* __restrict__ ds_sorted,
                    const int* __restrict__ eids,
                    const int* __restrict__ edge_src,
                    const int* __restrict__ edge_dst,
                    int use_ds,
                    const unsigned short* __restrict__ whi,
                    const unsigned short* __restrict__ wlo,
                    const float* __restrict__ b1,
                    const float* __restrict__ b2,
                    float* __restrict__ new_states)
{
  __shared__ __align__(16) unsigned short H2[4][2 * 16 * SH];  // h2 hi|lo; msg aliases

  const int t = threadIdx.x;
  const int w = t >> 6;
  const int l = t & 63;
  const int e0 = blockIdx.x * 64 + w * 16;

  unsigned short* h2 = H2[w];
  float* msg = (float*)H2[w];            // 16*SH floats = 4608 B = slice, exact

  // ---- indices: lanes 0..15 load, all lanes pick up via shfl
  int d = 0, s = 0;
  if (l < 16) {
    if (use_ds) {
      int2 ds = ds_sorted[e0 + l];
      d = ds.x; s = ds.y;
    } else {
      int eid = eids[e0 + l];
      d = edge_dst[eid];
      s = edge_src[eid];
    }
  }

  const int m  = l & 15;                 // this lane's edge within the tile
  const int dm = __shfl(d, m);
  const int sm = __shfl(s, m);
  const int fi = (l >> 4) * 2;           // float4 index within 32-float k-step
  const int cc = l & 15;

  // ---- gather h1 = relu(Yd[dst]+Ys[src]) straight into A-fragments
  bf16x8 a1h[2], a1l[2];
  {
    const float4* pd = (const float4*)(Yd + (size_t)dm * DD);
    const float4* ps = (const float4*)(Ys + (size_t)sm * DD);
#pragma unroll
    for (int s2 = 0; s2 < 2; ++s2) {
      float4 x0 = pd[s2 * 8 + fi], x1 = pd[s2 * 8 + fi + 1];
      float4 y0 = ps[s2 * 8 + fi], y1 = ps[s2 * 8 + fi + 1];
      float4 r0 = make_float4(relu(x0.x + y0.x), relu(x0.y + y0.y),
                              relu(x0.z + y0.z), relu(x0.w + y0.w));
      float4 r1 = make_float4(relu(x1.x + y1.x), relu(x1.y + y1.y),
                              relu(x1.z + y1.z), relu(x1.w + y1.w));
      mk_frag(r0, r1, a1h[s2], a1l[s2]);
    }
  }

  f32x4 acc[4];

  // ---- layer 1 (A = regs, B sec 2) -> h2 hi/lo in LDS (own slice)
#pragma unroll
  for (int j = 0; j < 4; ++j) acc[j] = (f32x4){0.f, 0.f, 0.f, 0.f};
#pragma unroll
  for (int s2 = 0; s2 < 2; ++s2) {
#pragma unroll
    for (int j = 0; j < 4; ++j) {
      const int fo = 2 * 4096 + ((j * 2 + s2) * 64 + l) * 8;
      bf16x8 bh = ldfrag(whi + fo);
      bf16x8 bl = ldfrag(wlo + fo);
      acc[j] = mfma16(a1l[s2], bh, acc[j]);
      acc[j] = mfma16(a1h[s2], bl, acc[j]);
      acc[j] = mfma16(a1h[s2], bh, acc[j]);
    }
  }
#pragma unroll
  for (int j = 0; j < 4; ++j) {
    const int   c  = j * 16 + cc;
    const float bb = b1[c];
#pragma unroll
    for (int i = 0; i < 4; ++i) {
      const int r = (l >> 4) * 4 + i;    // C layout rows 0..15
      float v = relu(acc[j][i] + bb);
      unsigned short hi = bfbits(v);
      h2[r * SH + c] = hi;
      h2[16 * SH + r * SH + c] = bfbits(v - bfval(hi));
    }
  }

  // ---- layer 2 (A = h2 from LDS, B sec 3) -> msg fp32 (aliases h2 slice;
  // same-wave in-order LDS: reads complete before epilogue writes)
  const int mrow = l & 15;
  const int kq   = (l >> 4) * 8;
#pragma unroll
  for (int j = 0; j < 4; ++j) acc[j] = (f32x4){0.f, 0.f, 0.f, 0.f};
#pragma unroll
  for (int s2 = 0; s2 < 2; ++s2) {
    bf16x8 ah = ldfrag(&h2[mrow * SH + s2 * 32 + kq]);
    bf16x8 al = ldfrag(&h2[16 * SH + mrow * SH + s2 * 32 + kq]);
#pragma unroll
    for (int j = 0; j < 4; ++j) {
      const int fo = 3 * 4096 + ((j * 2 + s2) * 64 + l) * 8;
      bf16x8 bh = ldfrag(whi + fo);
      bf16x8 bl = ldfrag(wlo + fo);
      acc[j] = mfma16(al, bh, acc[j]);
      acc[j] = mfma16(ah, bl, acc[j]);
      acc[j] = mfma16(ah, bh, acc[j]);
    }
  }
#pragma unroll
  for (int j = 0; j < 4; ++j) {
    const int   c  = j * 16 + cc;
    const float bb = b2[c];
#pragma unroll
    for (int i = 0; i < 4; ++i) {
      const int r = (l >> 4) * 4 + i;
      msg[r * SH + c] = relu(acc[j][i] + bb);
    }
  }

  // ---- per-wave segmented reduction: lane owns column l, walks 16 rows.
  {
    int   cur   = __shfl(d, 0);
    float run   = 0.f;
    bool  first = true;
#pragma unroll
    for (int r = 0; r < 16; ++r) {
      float v  = msg[r * SH + l];
      int   dr = __shfl(d, r);          // wave-uniform
      if (r > 0 && dr != cur) {
        float* p = new_states + (size_t)cur * DD + l;
        if (first) atomicAdd(p, run);
        else       *p = run;            // interior run: exclusive owner
        first = false;
        run = 0.f;
        cur = dr;
      }
      run += v;
    }
    atomicAdd(new_states + (size_t)cur * DD + l, run);  // last run
  }
}

// ===========================================================================
// atom_kernel_v2 (unchanged from R7 — proven): readout MFMA + fp32 out + mol sum.
// ===========================================================================
__global__ __launch_bounds__(256, 4)
void atom_kernel_v2(const float* __restrict__ ns,
                    const unsigned short* __restrict__ whi,
                    const unsigned short* __restrict__ wlo,
                    const float* __restrict__ f1b,
                    const float* __restrict__ f2b,
                    const float* __restrict__ wo,
                    const float* __restrict__ bo,
                    float* __restrict__ out)
{
  __shared__ __align__(16) unsigned short Xb[2 * 64 * SH];
  __shared__ __align__(16) unsigned short Hb[2 * 64 * SH];
  unsigned short* Xh = Xb;
  unsigned short* Xl = Xb + 64 * SH;
  unsigned short* Hh = Hb;
  unsigned short* Hl = Hb + 64 * SH;
  float* h2f = (float*)Xb;
  float* oS  = (float*)Hb;

  const int t  = threadIdx.x;
  const int a0 = blockIdx.x * 64;

  {
    const int r  = t >> 2;
    const int k0 = (t & 3) * 16;
    const float4* s4 = (const float4*)(ns + (size_t)(a0 + r) * DD + k0);
#pragma unroll
    for (int f = 0; f < 4; ++f) {
      float4 v = s4[f];
      ushort4 h, lo;
      h.x = bfbits(v.x); lo.x = bfbits(v.x - bfval(h.x));
      h.y = bfbits(v.y); lo.y = bfbits(v.y - bfval(h.y));
      h.z = bfbits(v.z); lo.z = bfbits(v.z - bfval(h.z));
      h.w = bfbits(v.w); lo.w = bfbits(v.w - bfval(h.w));
      *(ushort4*)&Xh[r * SH + k0 + f * 4] = h;
      *(ushort4*)&Xl[r * SH + k0 + f * 4] = lo;
    }
  }

  const int l    = t & 63;
  const int w    = t >> 6;
  const int mrow = w * 16 + (l & 15);
  const int kq   = (l >> 4) * 8;
  const int cc   = l & 15;

  f32x4 acc[4];

#pragma unroll
  for (int j = 0; j < 4; ++j) acc[j] = (f32x4){0.f, 0.f, 0.f, 0.f};
#pragma unroll
  for (int s = 0; s < 2; ++s) {
    bf16x8 ah = ldfrag(&Xh[mrow * SH + s * 32 + kq]);
    bf16x8 al = ldfrag(&Xl[mrow * SH + s * 32 + kq]);
#pragma unroll
    for (int j = 0; j < 4; ++j) {
      const int fo = 4 * 4096 + ((j * 2 + s) * 64 + l) * 8;
      bf16x8 bh = ldfrag(whi + fo);
      bf16x8 bl = ldfrag(wlo + fo);
      acc[j] = mfma16(al, bh, acc[j]);
      acc[j] = mfma16(ah, bl, acc[j]);
      acc[j] = mfma16(ah, bh, acc[j]);
    }
  }
#pragma unroll
  for (int j = 0; j < 4; ++j) {
    const int   c  = j * 16 + cc;
    const float bb = f1b[c];
#pragma unroll
    for (int i = 0; i < 4; ++i) {
      const int r = w * 16 + (l >> 4) * 4 + i;
      float v = relu(acc[j][i] + bb);
      unsigned short hi = bfbits(v);
      Hh[r * SH + c] = hi;
      Hl[r * SH + c] = bfbits(v - bfval(hi));
    }
  }
  __syncthreads();

#pragma unroll
  for (int j = 0; j < 4; ++j) acc[j] = (f32x4){0.f, 0.f, 0.f, 0.f};
#pragma unroll
  for (int s = 0; s < 2; ++s) {
    bf16x8 ah = ldfrag(&Hh[mrow * SH + s * 32 + kq]);
    bf16x8 al = ldfrag(&Hl[mrow * SH + s * 32 + kq]);
#pragma unroll
    for (int j = 0; j < 4; ++j) {
      const int fo = 5 * 4096 + ((j * 2 + s) * 64 + l) * 8;
      bf16x8 bh = ldfrag(whi + fo);
      bf16x8 bl = ldfrag(wlo + fo);
      acc[j] = mfma16(al, bh, acc[j]);
      acc[j] = mfma16(ah, bl, acc[j]);
      acc[j] = mfma16(ah, bh, acc[j]);
    }
  }
#pragma unroll
  for (int j = 0; j < 4; ++j) {
    const int   c  = j * 16 + cc;
    const float bb = f2b[c];
#pragma unroll
    for (int i = 0; i < 4; ++i) {
      const int r = w * 16 + (l >> 4) * 4 + i;
      h2f[r * SH + c] = relu(acc[j][i] + bb);
    }
  }
  __syncthreads();

  {
    const int r  = t >> 2;
    const int c4 = (t & 3) * 4;
    float o4[4] = {0.f, 0.f, 0.f, 0.f};
#pragma unroll 8
    for (int k = 0; k < 64; ++k) {
      const float a = h2f[r * SH + k];
      float4 bw = *(const float4*)&wo[k * OUTD + c4];
      o4[0] += a * bw.x; o4[1] += a * bw.y; o4[2] += a * bw.z; o4[3] += a * bw.w;
    }
#pragma unroll
    for (int j = 0; j < 4; ++j)
      oS[r * 17 + c4 + j] = relu(o4[j] + bo[c4 + j]);
  }
  __syncthreads();

  if (t < 32) {
    const int m = t >> 4;
    const int c = t & 15;
    float s = 0.f;
#pragma unroll
    for (int a = 0; a < 32; ++a) s += oS[(m * 32 + a) * 17 + c];
    out[(blockIdx.x * 2 + m) * OUTD + c] = s;
  }
}

// ===========================================================================
extern "C" void kernel_launch(void* const* d_in, const int* in_sizes, int n_in,
                              void* d_out, int out_size, void* d_ws, size_t ws_size,
                              hipStream_t stream) {
  const float* atom_states = (const float*)d_in[0];
  const int*   edge_src    = (const int*)d_in[1];
  const int*   edge_dst    = (const int*)d_in[2];
  const float* ms0_w = (const float*)d_in[4];
  const float* ms0_b = (const float*)d_in[5];
  const float* ms1_w = (const float*)d_in[6];
  const float* ms1_b = (const float*)d_in[7];
  const float* ms2_w = (const float*)d_in[8];
  const float* ms2_b = (const float*)d_in[9];
  const float* fc1_w = (const float*)d_in[10];
  const float* fc1_b = (const float*)d_in[11];
  const float* fc2_w = (const float*)d_in[12];
  const float* fc2_b = (const float*)d_in[13];
  const float* out_w = (const float*)d_in[14];
  const float* out_b = (const float*)d_in[15];

  char* ws = (char*)d_ws;
  float* new_states = (float*)ws;
  size_t off = (size_t)N_ATOMS * DD * sizeof(float);                   // 32 MiB
  int* eids     = (int*)(ws + off); off += (size_t)N_EDGES * 4;        // +4 MiB
  int* counters = (int*)(ws + off); off += (size_t)N_ATOMS * 4;        // +512 KiB
  int* cursor   = (int*)(ws + off); off += (size_t)N_ATOMS * 4;        // +512 KiB
  int* partial  = (int*)(ws + off); off += 4096;                       // +4 KiB
  unsigned short* whi = (unsigned short*)(ws + off); off += 24576 * 2; // +48 KiB
  unsigned short* wlo = (unsigned short*)(ws + off); off += 24576 * 2; // +48 KiB
  float* Yd = (float*)(ws + off); off += (size_t)N_ATOMS * DD * sizeof(float);
  float* Ys = (float*)(ws + off); off += (size_t)N_ATOMS * DD * sizeof(float);
  int2* ds_sorted = (int2*)(ws + off);
  const size_t need_ds = off + (size_t)N_EDGES * sizeof(int2);         // ~109 MiB
  const int use_ds = (ws_size >= need_ds) ? 1 : 0;   // constant across calls

  hipMemsetAsync(counters, 0, (size_t)N_ATOMS * 4, stream);

  fused_k1<<<6156, 256, 0, stream>>>(edge_dst, ms0_w, ms1_w, ms2_w, fc1_w, fc2_w,
                                     counters, new_states, whi, wlo);
  blocksum_kernel<<<512, 256, 0, stream>>>(counters, partial);
  scanwrite_kernel<<<512, 256, 0, stream>>>(counters, partial, cursor);
  fused_k2<<<6144, 256, 0, stream>>>(atom_states, edge_src, edge_dst, cursor,
                                     ds_sorted, eids, use_ds,
                                     whi, wlo, ms0_b, Yd, Ys);
  edge_kernel_v6<<<N_EDGES / 64, 256, 0, stream>>>(
      Yd, Ys, ds_sorted, eids, edge_src, edge_dst, use_ds,
      whi, wlo, ms1_b, ms2_b, new_states);
  atom_kernel_v2<<<N_ATOMS / 64, 256, 0, stream>>>(
      new_states, whi, wlo, fc1_b, fc2_b, out_w, out_b, (float*)d_out);
}